// Round 1
// baseline (289.356 us; speedup 1.0000x reference)
//
#include <hip/hip_runtime.h>
#include <hip/hip_bf16.h>
#include <math.h>

#define N_NODES 50000
#define N_EDGES 1600000
#define H 64
#define G_GRAPHS 512
#define C_CLS 2
#define BN_EPS 1e-5f
#define NBUCK 196           // buckets of 256 nodes: dst>>8 in [0,196)
#define BUCKCAP 16384       // fixed bucket capacity (mean 8192 -> huge headroom)
#define E4 (N_EDGES / 4)    // 400000
#define CSR_BLOCKS ((E4 + 511) / 512)   // 782
#define IOP 72              // padded LDS row stride (bf16)

typedef __attribute__((ext_vector_type(8))) short short8;
typedef __attribute__((ext_vector_type(4))) float floatx4;

__device__ __forceinline__ float bflo(unsigned int u) { return __uint_as_float(u << 16); }
__device__ __forceinline__ float bfhi(unsigned int u) { return __uint_as_float(u & 0xffff0000u); }
__device__ __forceinline__ unsigned int bf16_rne(float f) {
    unsigned int u = __float_as_uint(f);
    u += 0x7fffu + ((u >> 16) & 1u);
    return u >> 16;
}

// ---------- prep: transpose 5 weight matrices to bf16 wT[j*64+k]; pack x ----------
__global__ __launch_bounds__(256) void prep_kernel(
    const float* __restrict__ w2_0, const float* __restrict__ w1_1,
    const float* __restrict__ w2_1, const float* __restrict__ w1_2,
    const float* __restrict__ w2_2, unsigned short* __restrict__ wt,
    const float* __restrict__ x, uint2* __restrict__ xb) {
    int b = blockIdx.x, t = threadIdx.x;
    if (b < 5) {
        const float* w = (b == 0) ? w2_0 : (b == 1) ? w1_1 : (b == 2) ? w2_1
                         : (b == 3) ? w1_2 : w2_2;
        unsigned short* o = wt + b * (H * H);
        for (int idx = t; idx < H * H; idx += 256) {
            int k = idx >> 6, j = idx & 63;
            o[j * H + k] = (unsigned short)bf16_rne(w[idx]);
        }
    } else {
        int node = (b - 5) * 256 + t;
        if (node < N_NODES) {
            uint2 p;
            p.x = bf16_rne(x[node * 3 + 0]) | (bf16_rne(x[node * 3 + 1]) << 16);
            p.y = bf16_rne(x[node * 3 + 2]);
            xb[node] = p;
        }
    }
}

// ---------- CSR pass 1 (single pass): scatter edges into fixed-cap buckets ----------
__global__ __launch_bounds__(256) void scatter1_kernel(const int* __restrict__ src,
                                                       const int* __restrict__ dst,
                                                       int* __restrict__ gcnt,
                                                       int* __restrict__ gpacked) {
    __shared__ int bh[NBUCK];
    int t = threadIdx.x;
    if (t < NBUCK) bh[t] = 0;
    __syncthreads();
    int base = blockIdx.x * 512;

    int pkA[4], bkA[4], lrA[4]; bool vA = false;
    int pkB[4], bkB[4], lrB[4]; bool vB = false;
    {
        int i = base + t;
        if (i < E4) {
            vA = true;
            int4 s4 = ((const int4*)src)[i];
            int4 d4 = ((const int4*)dst)[i];
            bkA[0] = d4.x >> 8; pkA[0] = ((d4.x & 255) << 16) | s4.x; lrA[0] = atomicAdd(&bh[bkA[0]], 1);
            bkA[1] = d4.y >> 8; pkA[1] = ((d4.y & 255) << 16) | s4.y; lrA[1] = atomicAdd(&bh[bkA[1]], 1);
            bkA[2] = d4.z >> 8; pkA[2] = ((d4.z & 255) << 16) | s4.z; lrA[2] = atomicAdd(&bh[bkA[2]], 1);
            bkA[3] = d4.w >> 8; pkA[3] = ((d4.w & 255) << 16) | s4.w; lrA[3] = atomicAdd(&bh[bkA[3]], 1);
        }
    }
    {
        int i = base + 256 + t;
        if (i < E4) {
            vB = true;
            int4 s4 = ((const int4*)src)[i];
            int4 d4 = ((const int4*)dst)[i];
            bkB[0] = d4.x >> 8; pkB[0] = ((d4.x & 255) << 16) | s4.x; lrB[0] = atomicAdd(&bh[bkB[0]], 1);
            bkB[1] = d4.y >> 8; pkB[1] = ((d4.y & 255) << 16) | s4.y; lrB[1] = atomicAdd(&bh[bkB[1]], 1);
            bkB[2] = d4.z >> 8; pkB[2] = ((d4.z & 255) << 16) | s4.z; lrB[2] = atomicAdd(&bh[bkB[2]], 1);
            bkB[3] = d4.w >> 8; pkB[3] = ((d4.w & 255) << 16) | s4.w; lrB[3] = atomicAdd(&bh[bkB[3]], 1);
        }
    }
    __syncthreads();
    if (t < NBUCK) {
        int c = bh[t];
        bh[t] = c ? atomicAdd(&gcnt[t], c) : 0;
    }
    __syncthreads();
    if (vA) {
#pragma unroll
        for (int q = 0; q < 4; q++) gpacked[bkA[q] * BUCKCAP + bh[bkA[q]] + lrA[q]] = pkA[q];
    }
    if (vB) {
#pragma unroll
        for (int q = 0; q < 4; q++) gpacked[bkB[q] * BUCKCAP + bh[bkB[q]] + lrB[q]] = pkB[q];
    }
}

// ---------- CSR pass 2: per-bucket local CSR; bucket offset computed in-block ----------
__global__ __launch_bounds__(256) void bcsr_kernel(const int* __restrict__ gpacked,
                                                   const int* __restrict__ gcnt,
                                                   int* __restrict__ row_start,
                                                   int* __restrict__ edge_src) {
    __shared__ int cnt[256];
    __shared__ int pref[256];
    int b = blockIdx.x;
    int t = threadIdx.x;

    int v = (t < NBUCK) ? gcnt[t] : 0;
    pref[t] = v;
    __syncthreads();
    for (int off = 1; off < 256; off <<= 1) {
        int u = 0;
        if (t >= off) u = pref[t - off];
        __syncthreads();
        if (t >= off) pref[t] += u;
        __syncthreads();
    }
    int bs = (b > 0) ? pref[b - 1] : 0;
    int cnt_b = gcnt[b];
    if (b == 0 && t == 0) row_start[N_NODES] = N_EDGES;
    __syncthreads();

    const int* gp = gpacked + (size_t)b * BUCKCAP;
    cnt[t] = 0;
    __syncthreads();
    for (int i = t; i < cnt_b; i += 256) atomicAdd(&cnt[gp[i] >> 16], 1);
    __syncthreads();
    int c = cnt[t];
    pref[t] = c;
    __syncthreads();
    for (int off = 1; off < 256; off <<= 1) {
        int u = 0;
        if (t >= off) u = pref[t - off];
        __syncthreads();
        if (t >= off) pref[t] += u;
        __syncthreads();
    }
    int excl = pref[t] - c;
    int node = b * 256 + t;
    if (node < N_NODES) row_start[node] = bs + excl;
    cnt[t] = excl;
    __syncthreads();
    for (int i = t; i < cnt_b; i += 256) {
        int p = gp[i];
        int pos = atomicAdd(&cnt[p >> 16], 1);
        edge_src[bs + pos] = p & 0xffff;
    }
}

#define RED3(A) { A += __shfl_xor(A, 8); A += __shfl_xor(A, 16); A += __shfl_xor(A, 32); }
#define RED6(A) { A += __shfl_xor(A, 1); A += __shfl_xor(A, 2); A += __shfl_xor(A, 4); \
                  A += __shfl_xor(A, 8); A += __shfl_xor(A, 16); A += __shfl_xor(A, 32); }

// ---------- layer 1 fused: combined-pair gather, wave0 MFMA lin2, pooled into pool[] ----------
__global__ __launch_bounds__(512) void gin1_fused16_kernel(
    const float* __restrict__ x, const uint2* __restrict__ xb,
    const int* __restrict__ row_start, const int* __restrict__ edge_src,
    const float* __restrict__ w1, const float* __restrict__ b1,
    const float* __restrict__ bn_g, const float* __restrict__ bn_b,
    const float* __restrict__ bn_m, const float* __restrict__ bn_v,
    const unsigned short* __restrict__ w2t, const float* __restrict__ b2,
    __hip_bfloat16* __restrict__ hout, const int* __restrict__ batch,
    float* __restrict__ pool) {
    __shared__ unsigned short s_mid[16 * IOP];
    __shared__ int s_bat[16];

    int tid = threadIdx.x;
    int wave = tid >> 6, j = tid & 63;
    int nodebase = blockIdx.x * 16;     // 3125 blocks x 16 = 50000 exact
    if (tid < 16) s_bat[tid] = batch[nodebase + tid];

    float wj0 = w1[j], wj1 = w1[H + j], wj2 = w1[2 * H + j];
    float sc = rsqrtf(bn_v[j] + BN_EPS) * bn_g[j];
    float sh = bn_b[j] - bn_m[j] * sc;
    float bj = b1[j];

    // phase A: combined gather over [rs0, re1) for the wave's 2 contiguous nodes
    int n0 = nodebase + wave * 2;
    int rs0 = row_start[n0];
    int re0 = row_start[n0 + 1];
    int re1 = row_start[n0 + 2];
    int c0 = re0 - rs0;
    int total = re1 - rs0;

    float a00 = 0.f, a01 = 0.f, a02 = 0.f;
    float a10 = 0.f, a11 = 0.f, a12 = 0.f;
    for (int base = 0; base < total; base += 64) {
        int idx = rs0 + base + j;
        if (idx < re1) {
            uint2 p = xb[edge_src[idx]];
            if (base + j < c0) { a00 += bflo(p.x); a01 += bfhi(p.x); a02 += bflo(p.y); }
            else               { a10 += bflo(p.x); a11 += bfhi(p.x); a12 += bflo(p.y); }
        }
    }
    RED6(a00) RED6(a01) RED6(a02)
    RED6(a10) RED6(a11) RED6(a12)
    {
        float in0 = a00 + x[n0 * 3 + 0];
        float in1 = a01 + x[n0 * 3 + 1];
        float in2 = a02 + x[n0 * 3 + 2];
        float m = bj + in0 * wj0 + in1 * wj1 + in2 * wj2;
        m = fmaxf(m * sc + sh, 0.f);
        s_mid[(wave * 2) * IOP + j] = (unsigned short)bf16_rne(m);
    }
    {
        int n1 = n0 + 1;
        float in0 = a10 + x[n1 * 3 + 0];
        float in1 = a11 + x[n1 * 3 + 1];
        float in2 = a12 + x[n1 * 3 + 2];
        float m = bj + in0 * wj0 + in1 * wj1 + in2 * wj2;
        m = fmaxf(m * sc + sh, 0.f);
        s_mid[(wave * 2 + 1) * IOP + j] = (unsigned short)bf16_rne(m);
    }
    __syncthreads();

    // phase B: wave 0 computes relu(mid@w2+b2) for all 16 nodes, stores + pools
    if (wave == 0) {
        int quad = j >> 4, l15 = j & 15;
        float bb2[4];
#pragma unroll
        for (int jt = 0; jt < 4; jt++) bb2[jt] = b2[jt * 16 + l15];

        short8 m0 = *(const short8*)&s_mid[l15 * IOP + quad * 8];
        short8 m1 = *(const short8*)&s_mid[l15 * IOP + quad * 8 + 32];
        int bq0 = s_bat[quad * 4], bq3 = s_bat[quad * 4 + 3];
#pragma unroll
        for (int jt = 0; jt < 4; jt++) {
            short8 b0 = *(const short8*)&w2t[(jt * 16 + l15) * H + quad * 8];
            short8 bv = *(const short8*)&w2t[(jt * 16 + l15) * H + quad * 8 + 32];
            floatx4 c = {0.f, 0.f, 0.f, 0.f};
            c = __builtin_amdgcn_mfma_f32_16x16x32_bf16(m0, b0, c, 0, 0, 0);
            c = __builtin_amdgcn_mfma_f32_16x16x32_bf16(m1, bv, c, 0, 0, 0);
            float vv[4];
#pragma unroll
            for (int r = 0; r < 4; r++) {
                float v = fmaxf(c[r] + bb2[jt], 0.f);
                vv[r] = v;
                s_mid[(quad * 4 + r) * IOP + jt * 16 + l15] = (unsigned short)bf16_rne(v);
            }
            int jj = jt * 16 + l15;
            if (bq0 == bq3) {
                atomicAdd(&pool[bq0 * 192 + jj], (vv[0] + vv[1]) + (vv[2] + vv[3]));
            } else {
                atomicAdd(&pool[s_bat[quad * 4 + 0] * 192 + jj], vv[0]);
                atomicAdd(&pool[s_bat[quad * 4 + 1] * 192 + jj], vv[1]);
                atomicAdd(&pool[s_bat[quad * 4 + 2] * 192 + jj], vv[2]);
                atomicAdd(&pool[s_bat[quad * 4 + 3] * 192 + jj], vv[3]);
            }
        }
        unsigned short* ho = (unsigned short*)hout;
#pragma unroll
        for (int cc = 0; cc < 2; cc++) {
            int r = cc * 8 + (j >> 3);
            short8 v = *(const short8*)&s_mid[r * IOP + (j & 7) * 8];
            *(short8*)(ho + (size_t)(nodebase + r) * H + (j & 7) * 8) = v;
        }
    }
}

#define ACC8(R, A0, A1, A2, A3, A4, A5, A6, A7) { \
    A0 += bflo(R.x); A1 += bfhi(R.x); A2 += bflo(R.y); A3 += bfhi(R.y); \
    A4 += bflo(R.z); A5 += bfhi(R.z); A6 += bflo(R.w); A7 += bfhi(R.w); }

#define GROUP_ACC(R, r) { \
    if ((r) < lim) { \
        if ((base + (r)) < c0) { ACC8(R, a00, a01, a02, a03, a04, a05, a06, a07) } \
        else                   { ACC8(R, a10, a11, a12, a13, a14, a15, a16, a17) } \
    } }

// ---------- layers 2/3 fused: combined-pair gather (4 loads in flight), wave0 MFMA MLP, pooled ----------
__global__ __launch_bounds__(512) void gin_fused16_kernel(
    const __hip_bfloat16* __restrict__ hin, const int* __restrict__ row_start,
    const int* __restrict__ edge_src,
    const unsigned short* __restrict__ w1t, const float* __restrict__ b1,
    const float* __restrict__ bn_g, const float* __restrict__ bn_b,
    const float* __restrict__ bn_m, const float* __restrict__ bn_v,
    const unsigned short* __restrict__ w2t, const float* __restrict__ b2,
    __hip_bfloat16* __restrict__ hout, const int* __restrict__ batch,
    float* __restrict__ pool) {
    __shared__ unsigned short s_xs[16 * IOP];
    __shared__ unsigned short s_mid[16 * IOP];
    __shared__ int s_bat[16];

    int tid = threadIdx.x;
    int wave = tid >> 6, j = tid & 63;
    int o = j >> 3, jo = j & 7;
    int nodebase = blockIdx.x * 16;
    if (tid < 16) s_bat[tid] = batch[nodebase + tid];

    const char* hb = (const char*)hin;

    // phase A: combined gather over [rs0, re1) (the wave's 2 nodes are CSR-contiguous)
    int n0 = nodebase + wave * 2;
    int rs0 = row_start[n0];
    int re0 = row_start[n0 + 1];
    int re1 = row_start[n0 + 2];
    int c0 = re0 - rs0;
    int total = re1 - rs0;

    float a00 = 0.f, a01 = 0.f, a02 = 0.f, a03 = 0.f, a04 = 0.f, a05 = 0.f, a06 = 0.f, a07 = 0.f;
    float a10 = 0.f, a11 = 0.f, a12 = 0.f, a13 = 0.f, a14 = 0.f, a15 = 0.f, a16 = 0.f, a17 = 0.f;

    for (int base = 0; base < total; base += 64) {
        int idx = rs0 + base + j;
        int sv = (idx < re1) ? edge_src[idx] : 0;
        int lim = min(64, total - base);
#pragma unroll
        for (int i = 0; i < 64; i += 32) {
            if (i >= lim) break;
            int r0 = i + o, r1 = i + 8 + o, r2 = i + 16 + o, r3 = i + 24 + o;
            int s0 = __shfl(sv, r0);
            int s1 = __shfl(sv, r1);
            int s2 = __shfl(sv, r2);
            int s3 = __shfl(sv, r3);
            uint4 R0 = *(const uint4*)(hb + (size_t)s0 * 128 + jo * 16);
            uint4 R1 = *(const uint4*)(hb + (size_t)s1 * 128 + jo * 16);
            uint4 R2 = *(const uint4*)(hb + (size_t)s2 * 128 + jo * 16);
            uint4 R3 = *(const uint4*)(hb + (size_t)s3 * 128 + jo * 16);
            GROUP_ACC(R0, r0)
            GROUP_ACC(R1, r1)
            GROUP_ACC(R2, r2)
            GROUP_ACC(R3, r3)
        }
    }
    // butterfly over the octet dimension: every lane ends with the full sum for its jo slice
    RED3(a00) RED3(a01) RED3(a02) RED3(a03) RED3(a04) RED3(a05) RED3(a06) RED3(a07)
    RED3(a10) RED3(a11) RED3(a12) RED3(a13) RED3(a14) RED3(a15) RED3(a16) RED3(a17)

    if (o < 2) {
        int nl = wave * 2 + o;
        float r0 = (o == 0) ? a00 : a10, r1 = (o == 0) ? a01 : a11;
        float r2 = (o == 0) ? a02 : a12, r3 = (o == 0) ? a03 : a13;
        float r4 = (o == 0) ? a04 : a14, r5 = (o == 0) ? a05 : a15;
        float r6 = (o == 0) ? a06 : a16, r7 = (o == 0) ? a07 : a17;
        uint4 raw = *(const uint4*)(hb + (size_t)(nodebase + nl) * 128 + jo * 16);
        r0 += bflo(raw.x); r1 += bfhi(raw.x);
        r2 += bflo(raw.y); r3 += bfhi(raw.y);
        r4 += bflo(raw.z); r5 += bfhi(raw.z);
        r6 += bflo(raw.w); r7 += bfhi(raw.w);
        uint4 ov;
        ov.x = bf16_rne(r0) | (bf16_rne(r1) << 16);
        ov.y = bf16_rne(r2) | (bf16_rne(r3) << 16);
        ov.z = bf16_rne(r4) | (bf16_rne(r5) << 16);
        ov.w = bf16_rne(r6) | (bf16_rne(r7) << 16);
        *(uint4*)&s_xs[nl * IOP + jo * 8] = ov;
    }
    __syncthreads();

    // phase B: wave 0 runs the full MLP for all 16 nodes, stores + pools
    if (wave == 0) {
        int quad = j >> 4, l15 = j & 15;
        float scl[4], sht[4], bb1[4], bb2[4];
#pragma unroll
        for (int jt = 0; jt < 4; jt++) {
            int jj = jt * 16 + l15;
            float sc = rsqrtf(bn_v[jj] + BN_EPS) * bn_g[jj];
            scl[jt] = sc;
            sht[jt] = bn_b[jj] - bn_m[jj] * sc;
            bb1[jt] = b1[jj];
            bb2[jt] = b2[jj];
        }
        short8 a0 = *(const short8*)&s_xs[l15 * IOP + quad * 8];
        short8 a1 = *(const short8*)&s_xs[l15 * IOP + quad * 8 + 32];
#pragma unroll
        for (int jt = 0; jt < 4; jt++) {
            short8 b0 = *(const short8*)&w1t[(jt * 16 + l15) * H + quad * 8];
            short8 bv = *(const short8*)&w1t[(jt * 16 + l15) * H + quad * 8 + 32];
            floatx4 c = {0.f, 0.f, 0.f, 0.f};
            c = __builtin_amdgcn_mfma_f32_16x16x32_bf16(a0, b0, c, 0, 0, 0);
            c = __builtin_amdgcn_mfma_f32_16x16x32_bf16(a1, bv, c, 0, 0, 0);
#pragma unroll
            for (int r = 0; r < 4; r++) {
                float v = (c[r] + bb1[jt]) * scl[jt] + sht[jt];
                v = fmaxf(v, 0.f);
                s_mid[(quad * 4 + r) * IOP + jt * 16 + l15] = (unsigned short)bf16_rne(v);
            }
        }
        short8 m0 = *(const short8*)&s_mid[l15 * IOP + quad * 8];
        short8 m1 = *(const short8*)&s_mid[l15 * IOP + quad * 8 + 32];
        int bq0 = s_bat[quad * 4], bq3 = s_bat[quad * 4 + 3];
#pragma unroll
        for (int jt = 0; jt < 4; jt++) {
            short8 b0 = *(const short8*)&w2t[(jt * 16 + l15) * H + quad * 8];
            short8 bv = *(const short8*)&w2t[(jt * 16 + l15) * H + quad * 8 + 32];
            floatx4 c = {0.f, 0.f, 0.f, 0.f};
            c = __builtin_amdgcn_mfma_f32_16x16x32_bf16(m0, b0, c, 0, 0, 0);
            c = __builtin_amdgcn_mfma_f32_16x16x32_bf16(m1, bv, c, 0, 0, 0);
            float vv[4];
#pragma unroll
            for (int r = 0; r < 4; r++) {
                float v = fmaxf(c[r] + bb2[jt], 0.f);
                vv[r] = v;
                s_xs[(quad * 4 + r) * IOP + jt * 16 + l15] = (unsigned short)bf16_rne(v);
            }
            int jj = jt * 16 + l15;
            if (bq0 == bq3) {
                atomicAdd(&pool[bq0 * 192 + jj], (vv[0] + vv[1]) + (vv[2] + vv[3]));
            } else {
                atomicAdd(&pool[s_bat[quad * 4 + 0] * 192 + jj], vv[0]);
                atomicAdd(&pool[s_bat[quad * 4 + 1] * 192 + jj], vv[1]);
                atomicAdd(&pool[s_bat[quad * 4 + 2] * 192 + jj], vv[2]);
                atomicAdd(&pool[s_bat[quad * 4 + 3] * 192 + jj], vv[3]);
            }
        }
        unsigned short* ho = (unsigned short*)hout;
#pragma unroll
        for (int cc = 0; cc < 2; cc++) {
            int r = cc * 8 + (j >> 3);
            short8 v = *(const short8*)&s_xs[r * IOP + (j & 7) * 8];
            *(short8*)(ho + (size_t)(nodebase + r) * H + (j & 7) * 8) = v;
        }
    }
}

// ---------- head: pooled rows already in pool[]; tiny MLP + log_softmax ----------
__global__ __launch_bounds__(192) void head_kernel(
    const float* __restrict__ pool,
    const float* __restrict__ lin1_w, const float* __restrict__ lin1_b,
    const float* __restrict__ lin2_w, const float* __restrict__ lin2_b,
    float* __restrict__ out) {
    __shared__ float s_row[3 * H];
    __shared__ float s_mid[3 * H];
    __shared__ float s_z[C_CLS];

    int g = blockIdx.x;
    int j = threadIdx.x;
    s_row[j] = pool[g * 192 + j];
    __syncthreads();

    float acc = lin1_b[j];
    for (int k = 0; k < 3 * H; k++) acc += s_row[k] * lin1_w[k * (3 * H) + j];
    s_mid[j] = fmaxf(acc, 0.f);
    __syncthreads();

    if (j < C_CLS) {
        float z = lin2_b[j];
        for (int k = 0; k < 3 * H; k++) z += s_mid[k] * lin2_w[k * C_CLS + j];
        s_z[j] = z;
    }
    __syncthreads();
    if (j < C_CLS) {
        float z0 = s_z[0], z1 = s_z[1];
        float mx = fmaxf(z0, z1);
        float lse = mx + logf(expf(z0 - mx) + expf(z1 - mx));
        out[g * C_CLS + j] = s_z[j];
        out[G_GRAPHS * C_CLS + g * C_CLS + j] = s_z[j] - lse;
    }
}

extern "C" void kernel_launch(void* const* d_in, const int* in_sizes, int n_in,
                              void* d_out, int out_size, void* d_ws, size_t ws_size,
                              hipStream_t stream) {
    const float* x = (const float*)d_in[0];
    const float* cw1[3], *cb1[3], *cg[3], *cbb[3], *cm[3], *cv[3], *cw2[3], *cb2[3];
    for (int l = 0; l < 3; l++) {
        int b = 1 + 8 * l;
        cw1[l] = (const float*)d_in[b + 0];
        cb1[l] = (const float*)d_in[b + 1];
        cg[l]  = (const float*)d_in[b + 2];
        cbb[l] = (const float*)d_in[b + 3];
        cm[l]  = (const float*)d_in[b + 4];
        cv[l]  = (const float*)d_in[b + 5];
        cw2[l] = (const float*)d_in[b + 6];
        cb2[l] = (const float*)d_in[b + 7];
    }
    const float* lin1_w = (const float*)d_in[25];
    const float* lin1_b = (const float*)d_in[26];
    const float* lin2_w = (const float*)d_in[27];
    const float* lin2_b = (const float*)d_in[28];
    const int* edge_index = (const int*)d_in[29];
    const int* batch = (const int*)d_in[30];
    const int* src = edge_index;
    const int* dst = edge_index + N_EDGES;
    float* out = (float*)d_out;

    // workspace layout
    int* edge_src = (int*)d_ws;                     // E
    int* gpacked = edge_src + N_EDGES;              // NBUCK*BUCKCAP (12.8 MB)
    int* gcnt = gpacked + (size_t)NBUCK * BUCKCAP;  // NBUCK
    float* pool = (float*)(gcnt + NBUCK);           // G*192 f32 (zeroed with gcnt)
    int* row_start = (int*)(pool + G_GRAPHS * 3 * H);  // N+2
    uintptr_t hp = (uintptr_t)(row_start + N_NODES + 2);
    hp = (hp + 127) & ~(uintptr_t)127;
    unsigned short* wt = (unsigned short*)hp;       // 5 * H*H bf16
    uint2* xb = (uint2*)(wt + 5 * H * H);           // N
    __hip_bfloat16* h1 = (__hip_bfloat16*)(xb + N_NODES);  // N*H each
    __hip_bfloat16* h2 = h1 + (size_t)N_NODES * H;
    __hip_bfloat16* h3 = h2 + (size_t)N_NODES * H;

    const unsigned short* w2t_0 = wt + 0 * H * H;
    const unsigned short* w1t_1 = wt + 1 * H * H;
    const unsigned short* w2t_1 = wt + 2 * H * H;
    const unsigned short* w1t_2 = wt + 3 * H * H;
    const unsigned short* w2t_2 = wt + 4 * H * H;

    // ---- prep + CSR build (one memset covers gcnt + pool, they are adjacent) ----
    hipMemsetAsync(gcnt, 0, NBUCK * sizeof(int) + G_GRAPHS * 3 * H * sizeof(float), stream);
    prep_kernel<<<5 + (N_NODES + 255) / 256, 256, 0, stream>>>(
        cw2[0], cw1[1], cw2[1], cw1[2], cw2[2], wt, x, xb);
    scatter1_kernel<<<CSR_BLOCKS, 256, 0, stream>>>(src, dst, gcnt, gpacked);
    bcsr_kernel<<<NBUCK, 256, 0, stream>>>(gpacked, gcnt, row_start, edge_src);

    const int fgrid = N_NODES / 16;   // 3125, exact

    // ---- layer 1 ----
    gin1_fused16_kernel<<<fgrid, 512, 0, stream>>>(x, xb, row_start, edge_src,
        cw1[0], cb1[0], cg[0], cbb[0], cm[0], cv[0], w2t_0, cb2[0], h1, batch, pool);
    // ---- layer 2 ----
    gin_fused16_kernel<<<fgrid, 512, 0, stream>>>(h1, row_start, edge_src,
        w1t_1, cb1[1], cg[1], cbb[1], cm[1], cv[1], w2t_1, cb2[1], h2, batch, pool + 64);
    // ---- layer 3 ----
    gin_fused16_kernel<<<fgrid, 512, 0, stream>>>(h2, row_start, edge_src,
        w1t_2, cb1[2], cg[2], cbb[2], cm[2], cv[2], w2t_2, cb2[2], h3, batch, pool + 128);
    // ---- head (pool already accumulated by the layer kernels) ----
    head_kernel<<<G_GRAPHS, 3 * H, 0, stream>>>(pool,
        lin1_w, lin1_b, lin2_w, lin2_b, out);
}